// Round 9
// baseline (517.057 us; speedup 1.0000x reference)
//
#include <hip/hip_runtime.h>
#include <hip/hip_bf16.h>

// VAE_RNN: B=4096, T=200, D=128, L=64, H=128, CIN=2L+D=256
// Persistent-block RNN, 256 blocks x 512 threads (8 symmetric waves),
// 16 rows/block, 200 steps. Weights register-resident.
// R9: x NEVER touches LDS. Each wave loads x fragments DIRECTLY from global
// in MFMA fragment layout (lane -> x[row0+lc][kt*32+lq*8..+8]); loads for
// x(t+2) issue in P4(t) (2 phases of latency cover), f32->bf16 conversion in
// P2's shadow, and the state-independent partials A_x/C_x run in P3/P4
// shadows, carried across the step boundary in accumulator registers.
//   P1: A_ys(t) [4kt, acc=carried Ax] -> tanh -> t_lds
//   P2: B(t) [4kt] -> sigmoid -> u(regs/u_lds) | hc=y*r,s*r in place
//       + convert staged x(t+1) frags (VALU shadow)
//   P3: C_hc(t) [4kt, acc=carried Cx] -> tanh -> tn_lds ; + A_x(t+1) [8 MFMA]
//   P4: D(t) [4kt] -> EMA (fp32 regs) -> publish y,s bf16
//       + issue x(t+2) global loads ; + C_x(t+1) [4 MFMA]
// h tile is [y|s] only (256B/row). 4 lgkm-only barriers/step.

#define NB 4096
#define NT 200
#define ND 128
#define HSB 272     // h / tn row stride (bytes)
#define TSB 528     // t row stride (bytes)

typedef __bf16 bf16;
typedef __attribute__((ext_vector_type(8))) __bf16 bf16x8;
typedef __attribute__((ext_vector_type(4))) __bf16 bf16x4;
typedef __attribute__((ext_vector_type(4))) float f32x4;

#define BAR() asm volatile("s_waitcnt lgkmcnt(0)\n\ts_barrier" ::: "memory")

__device__ __forceinline__ f32x4 mfma16(bf16x8 a, bf16x8 b, f32x4 c){
    return __builtin_amdgcn_mfma_f32_16x16x32_bf16(a, b, c, 0, 0, 0);
}
// inf-safe, branch-free
__device__ __forceinline__ float fast_tanh(float x){
    float e = __expf(2.f * x);
    return 1.f - 2.f * __builtin_amdgcn_rcpf(e + 1.f);
}
__device__ __forceinline__ float fast_sigmoid(float x){
    return __builtin_amdgcn_rcpf(1.f + __expf(-x));
}
__device__ __forceinline__ bf16x4 tanh4(f32x4 a){
    bf16x4 o;
    o[0] = (bf16)fast_tanh(a[0]);
    o[1] = (bf16)fast_tanh(a[1]);
    o[2] = (bf16)fast_tanh(a[2]);
    o[3] = (bf16)fast_tanh(a[3]);
    return o;
}
__device__ __forceinline__ f32x4 bias4(const float* b, int f){
    f32x4 r; r[0]=b[f]; r[1]=b[f+1]; r[2]=b[f+2]; r[3]=b[f+3]; return r;
}

__global__ __launch_bounds__(512, 2)
void vae_rnn(const float* __restrict__ data,
             const float* __restrict__ ug_w1, const float* __restrict__ ug_b1,
             const float* __restrict__ ug_w2, const float* __restrict__ ug_b2,
             const float* __restrict__ rg_w1, const float* __restrict__ rg_b1,
             const float* __restrict__ rg_w2, const float* __restrict__ rg_b2,
             const float* __restrict__ ns_w1, const float* __restrict__ ns_b1,
             const float* __restrict__ ns_w2, const float* __restrict__ ns_b2,
             float* __restrict__ out)
{
    __shared__ __align__(16) char h_lds [16 * HSB];  // [y|s] bf16 (hc in place)
    __shared__ __align__(16) char t_lds [16 * TSB];  // tanh(l1) [ug|rg] bf16
    __shared__ __align__(16) char tn_lds[16 * HSB];  // tanh(l1) ns bf16
    __shared__ float u_lds[16][68];                  // u gate fp32 (std waves)

    const int tid  = threadIdx.x;
    const int w    = tid >> 6;
    const int lane = tid & 63;
    const int lq   = lane >> 4;
    const int lc   = lane & 15;          // batch row within tile
    const int row0 = blockIdx.x * 16;

    const bool UG = (w < 4);             // ug side / u-role / mean-role
    const int fA = w * 32;               // A feats (256 over 8 waves)
    const int fB = (w & 3) * 16;         // B gate feats (64 per role)
    const int fC = w * 16;               // C feats (128 over 8 waves)
    const int fD = w * 16;               // D feats (mean 0:64, std 64:128)

    const float* W1 = UG ? ug_w1 : rg_w1;
    const float* B1 = UG ? ug_b1 : rg_b1;
    const float* W2 = UG ? ug_w2 : rg_w2;
    const float* B2 = UG ? ug_b2 : rg_b2;

    // ---------------- persistent weight fragments ----------------
    bf16x8 wAy[8], wAx[8]; f32x4 bA[2];
    #pragma unroll
    for (int j = 0; j < 2; ++j){
        int n = (fA + j*16 + lc) & 127;
        bA[j] = bias4(B1, (fA + j*16 + lq*4) & 127);
        #pragma unroll
        for (int kt = 0; kt < 4; ++kt){
            bf16x8 fy, fx;
            #pragma unroll
            for (int e = 0; e < 8; ++e){
                fy[e] = (bf16)W1[(      kt*32 + lq*8 + e)*128 + n];
                fx[e] = (bf16)W1[(128 + kt*32 + lq*8 + e)*128 + n];
            }
            wAy[kt*2 + j] = fy; wAx[kt*2 + j] = fx;
        }
    }
    bf16x8 wB[4]; f32x4 bB = bias4(B2, fB + lq*4);
    {
        int n = fB + lc;
        #pragma unroll
        for (int kt = 0; kt < 4; ++kt){
            bf16x8 f;
            #pragma unroll
            for (int e = 0; e < 8; ++e) f[e] = (bf16)W2[(kt*32 + lq*8 + e)*64 + n];
            wB[kt] = f;
        }
    }
    bf16x8 wCh[4], wCx[4]; f32x4 bC = bias4(ns_b1, fC + lq*4);
    {
        int n = fC + lc;
        #pragma unroll
        for (int kt = 0; kt < 4; ++kt){
            bf16x8 fh, fx;
            #pragma unroll
            for (int e = 0; e < 8; ++e){
                fh[e] = (bf16)ns_w1[(      kt*32 + lq*8 + e)*128 + n];
                fx[e] = (bf16)ns_w1[(128 + kt*32 + lq*8 + e)*128 + n];
            }
            wCh[kt] = fh; wCx[kt] = fx;
        }
    }
    bf16x8 wD[4]; f32x4 bD = bias4(ns_b2, fD + lq*4);
    {
        int n = fD + lc;
        #pragma unroll
        for (int kt = 0; kt < 4; ++kt){
            bf16x8 f;
            #pragma unroll
            for (int e = 0; e < 8; ++e) f[e] = (bf16)ns_w2[(kt*32 + lq*8 + e)*128 + n];
            wD[kt] = f;
        }
    }

    // ---------------- LDS pointers (loop-invariant) ----------------
    const char* h_ys_rd = h_lds + lc*HSB + lq*16;          // + kt*64 (y,s / hc)
    char*       t_wr    = t_lds + lc*TSB + 2*(fA + lq*4);  // + j*32
    const char* t_rd    = t_lds + lc*TSB + lq*16 + (UG ? 0 : 256);
    char*       tn_wr   = tn_lds + lc*HSB + 2*(fC + lq*4);
    const char* tn_rd   = tn_lds + lc*HSB + lq*16;         // + kt*64
    char*       h_st_wr = h_lds + lc*HSB + 2*(fD + lq*4);  // y/s publish
    char*       ys_rw   = h_lds + lc*HSB + 2*(fB + lq*4);  // r-wave rw; +128 s

    // x fragment source: lane reads x[row0+lc][kt*32 + lq*8 .. +8] (32B/kt)
    const float* xf_src = data + (size_t)(row0 + lc) * (size_t)(NT * ND) + lq*8;

    // ---------------- prologue ----------------
    *(bf16x4*)(h_lds + (tid >> 5)*HSB + (tid & 31)*8) = (bf16x4){};  // ys = 0

    float4 xg[8];        // staged f32 x frags (loads in flight)
    bf16x8 xb[4];        // bf16 x frags of x(t+1)
    f32x4 Ax0, Ax1, Cx;  // carried x-partials (incl. bias)
    {
        // x(0) frags -> Ax(0), Cx(0)
        #pragma unroll
        for (int kt = 0; kt < 4; ++kt){
            xg[2*kt]   = *(const float4*)(xf_src + kt*32);
            xg[2*kt+1] = *(const float4*)(xf_src + kt*32 + 4);
        }
        #pragma unroll
        for (int kt = 0; kt < 4; ++kt){
            float4 a = xg[2*kt], b = xg[2*kt+1];
            xb[kt] = (bf16x8){ (bf16)a.x,(bf16)a.y,(bf16)a.z,(bf16)a.w,
                               (bf16)b.x,(bf16)b.y,(bf16)b.z,(bf16)b.w };
        }
        Ax0 = bA[0]; Ax1 = bA[1]; Cx = bC;
        #pragma unroll
        for (int kt = 0; kt < 4; ++kt){
            Ax0 = mfma16(wAx[kt*2+0], xb[kt], Ax0);
            Ax1 = mfma16(wAx[kt*2+1], xb[kt], Ax1);
            Cx  = mfma16(wCx[kt],     xb[kt], Cx);
        }
        // stage x(1)
        #pragma unroll
        for (int kt = 0; kt < 4; ++kt){
            xg[2*kt]   = *(const float4*)(xf_src + ND + kt*32);
            xg[2*kt+1] = *(const float4*)(xf_src + ND + kt*32 + 4);
        }
    }
    f32x4 st = {0.f,0.f,0.f,0.f};        // y-state (mean waves) / s-state
    f32x4 ug_reg = {0.f,0.f,0.f,0.f};
    BAR();

    #pragma unroll 1
    for (int t = 0; t < NT; ++t){
        // ---- P1: A_ys(t), acc = carried A_x(t) ----
        {
            f32x4 a0 = Ax0, a1 = Ax1;
            #pragma unroll
            for (int kt = 0; kt < 4; ++kt){
                bf16x8 hv = *(const bf16x8*)(h_ys_rd + kt*64);
                a0 = mfma16(wAy[kt*2+0], hv, a0);
                a1 = mfma16(wAy[kt*2+1], hv, a1);
            }
            *(bf16x4*)(t_wr +  0) = tanh4(a0);
            *(bf16x4*)(t_wr + 32) = tanh4(a1);
        }
        BAR();

        // ---- P2: B(t); convert staged x(t+1) frags in shadow ----
        {
            f32x4 b0 = bB, b1 = {0.f,0.f,0.f,0.f};
            #pragma unroll
            for (int kt = 0; kt < 4; ++kt){
                bf16x8 tv = *(const bf16x8*)(t_rd + kt*64);
                if (kt & 1) b1 = mfma16(wB[kt], tv, b1);
                else        b0 = mfma16(wB[kt], tv, b0);
            }
            #pragma unroll
            for (int kt = 0; kt < 4; ++kt){
                float4 a = xg[2*kt], b = xg[2*kt+1];
                xb[kt] = (bf16x8){ (bf16)a.x,(bf16)a.y,(bf16)a.z,(bf16)a.w,
                                   (bf16)b.x,(bf16)b.y,(bf16)b.z,(bf16)b.w };
            }
            f32x4 bs = b0 + b1;
            float g0 = fast_sigmoid(bs[0]);
            float g1 = fast_sigmoid(bs[1]);
            float g2 = fast_sigmoid(bs[2]);
            float g3 = fast_sigmoid(bs[3]);
            if (UG){
                ug_reg[0] = g0; ug_reg[1] = g1; ug_reg[2] = g2; ug_reg[3] = g3;
                *(f32x4*)&u_lds[lc][fB + lq*4] = ug_reg;
            } else {
                bf16x4 yv = *(const bf16x4*)(ys_rw);
                bf16x4 sv = *(const bf16x4*)(ys_rw + 128);
                bf16x4 hy = { (bf16)((float)yv[0]*g0), (bf16)((float)yv[1]*g1),
                              (bf16)((float)yv[2]*g2), (bf16)((float)yv[3]*g3) };
                bf16x4 hs = { (bf16)((float)sv[0]*g0), (bf16)((float)sv[1]*g1),
                              (bf16)((float)sv[2]*g2), (bf16)((float)sv[3]*g3) };
                *(bf16x4*)(ys_rw)       = hy;     // hc y*r over y cols
                *(bf16x4*)(ys_rw + 128) = hs;     // hc s*r over s cols
            }
        }
        BAR();

        // ---- P3: C_hc(t) (acc = carried C_x(t)); A_x(t+1) in shadow ----
        {
            f32x4 c0 = Cx, c1 = {0.f,0.f,0.f,0.f};
            #pragma unroll
            for (int kt = 0; kt < 4; ++kt){
                bf16x8 hv = *(const bf16x8*)(h_ys_rd + kt*64);
                if (kt & 1) c1 = mfma16(wCh[kt], hv, c1);
                else        c0 = mfma16(wCh[kt], hv, c0);
            }
            f32x4 ax0 = bA[0], ax1 = bA[1];
            ax0 = mfma16(wAx[0], xb[0], ax0);  ax1 = mfma16(wAx[1], xb[0], ax1);
            ax0 = mfma16(wAx[2], xb[1], ax0);  ax1 = mfma16(wAx[3], xb[1], ax1);
            ax0 = mfma16(wAx[4], xb[2], ax0);  ax1 = mfma16(wAx[5], xb[2], ax1);
            ax0 = mfma16(wAx[6], xb[3], ax0);  ax1 = mfma16(wAx[7], xb[3], ax1);
            Ax0 = ax0; Ax1 = ax1;
            f32x4 cs = c0 + c1;
            *(bf16x4*)tn_wr = tanh4(cs);
        }
        BAR();

        // ---- P4: issue x(t+2) loads; D(t); EMA; C_x(t+1); publish y,s ----
        {
            int t2 = (t + 2 < NT) ? (t + 2) : (NT - 1);
            const float* xp = xf_src + (size_t)t2 * ND;
            #pragma unroll
            for (int kt = 0; kt < 4; ++kt){
                xg[2*kt]   = *(const float4*)(xp + kt*32);
                xg[2*kt+1] = *(const float4*)(xp + kt*32 + 4);
            }
            f32x4 uu = ug_reg;
            if (!UG) uu = *(const f32x4*)&u_lds[lc][fB + lq*4];
            f32x4 d0 = bD, d1 = {0.f,0.f,0.f,0.f};
            #pragma unroll
            for (int kt = 0; kt < 4; ++kt){
                bf16x8 tv = *(const bf16x8*)(tn_rd + kt*64);
                if (kt & 1) d1 = mfma16(wD[kt], tv, d1);
                else        d0 = mfma16(wD[kt], tv, d0);
            }
            f32x4 cx = bC;
            cx = mfma16(wCx[0], xb[0], cx);
            cx = mfma16(wCx[1], xb[1], cx);
            cx = mfma16(wCx[2], xb[2], cx);
            cx = mfma16(wCx[3], xb[3], cx);
            Cx = cx;
            f32x4 ds = d0 + d1;
            #pragma unroll
            for (int i = 0; i < 4; ++i){
                float v = UG ? ds[i] : fabsf(ds[i]);
                st[i] = fmaf(uu[i], st[i] - v, v);
            }
            bf16x4 hn = { (bf16)st[0], (bf16)st[1], (bf16)st[2], (bf16)st[3] };
            *(bf16x4*)h_st_wr = hn;
        }
        BAR();
    }

    // ---------------- output: yT (4096x64) then sT (4096x64), fp32 ----------
    {
        size_t gr = (size_t)(row0 + lc);
        float4 v = make_float4(st[0], st[1], st[2], st[3]);
        if (UG) *(float4*)&out[gr*64 + fD + lq*4] = v;
        else    *(float4*)&out[(size_t)NB*64 + gr*64 + (fD - 64) + lq*4] = v;
    }
}

extern "C" void kernel_launch(void* const* d_in, const int* in_sizes, int n_in,
                              void* d_out, int out_size, void* d_ws, size_t ws_size,
                              hipStream_t stream) {
    const float* data  = (const float*)d_in[0];
    // d_in[1] = time_steps — unused by the reference computation
    const float* ug_w1 = (const float*)d_in[2];
    const float* ug_b1 = (const float*)d_in[3];
    const float* ug_w2 = (const float*)d_in[4];
    const float* ug_b2 = (const float*)d_in[5];
    const float* rg_w1 = (const float*)d_in[6];
    const float* rg_b1 = (const float*)d_in[7];
    const float* rg_w2 = (const float*)d_in[8];
    const float* rg_b2 = (const float*)d_in[9];
    const float* ns_w1 = (const float*)d_in[10];
    const float* ns_b1 = (const float*)d_in[11];
    const float* ns_w2 = (const float*)d_in[12];
    const float* ns_b2 = (const float*)d_in[13];

    hipLaunchKernelGGL(vae_rnn, dim3(NB/16), dim3(512), 0, stream,
                       data, ug_w1, ug_b1, ug_w2, ug_b2,
                       rg_w1, rg_b1, rg_w2, rg_b2,
                       ns_w1, ns_b1, ns_w2, ns_b2,
                       (float*)d_out);
}

// Round 10
// 341.129 us; speedup vs baseline: 1.5157x; 1.5157x over previous
//
#include <hip/hip_runtime.h>
#include <hip/hip_bf16.h>

// VAE_RNN: B=4096, T=200, D=128, L=64, H=128, CIN=2L+D=256
// Persistent-block RNN, 256 blocks x 512 threads (8 symmetric waves),
// 16 rows/block, 200 steps. Weights register-resident. x via LDS (R9's
// global-direct x refuted: fragment gather kills coalescing).
// R10 = R8 (324us) + latency retiming:
//   P1: A_ys(t) [8 MFMA, 4x 2-deep chains, acc=carried Ax] -> tanh -> t_lds
//       + xf reads (x(t+1) frags; consumers in P2/P3 -> pure overlap)
//       + r-waves pre-read y,s bf16 (for P2's hc)
//       + global load xn = x(t+2) (published in P4)
//   P2: B(t) [4 MFMA] -> sigmoid -> u (regs + u_lds) | hc = y*r,s*r in place
//       + A_x(t+1) [8 MFMA on xf, 4x 2-deep chains]
//   P3: C_hc(t) [4 MFMA, acc=carried Cx] -> tanh -> tn_lds
//       + C_x(t+1) [4 MFMA on xf, 2x 2-deep] + std-waves read u_lds (for P4)
//   P4: D(t) [4 MFMA] -> EMA (fp32 regs) -> publish y,s bf16
//       + publish x(t+2) from xn (3 phases of vmcnt cover)
// 4 lgkm-only barriers/step (vmcnt stays in flight across barriers).

#define NB 4096
#define NT 200
#define ND 128
#define HS 528      // h/t row stride bytes (33 x 16B)
#define TS 272      // tn row stride bytes (17 x 16B)

typedef __bf16 bf16;
typedef __attribute__((ext_vector_type(8))) __bf16 bf16x8;
typedef __attribute__((ext_vector_type(4))) __bf16 bf16x4;
typedef __attribute__((ext_vector_type(4))) float f32x4;

#define BAR() asm volatile("s_waitcnt lgkmcnt(0)\n\ts_barrier" ::: "memory")

__device__ __forceinline__ f32x4 mfma16(bf16x8 a, bf16x8 b, f32x4 c){
    return __builtin_amdgcn_mfma_f32_16x16x32_bf16(a, b, c, 0, 0, 0);
}
// inf-safe, branch-free
__device__ __forceinline__ float fast_tanh(float x){
    float e = __expf(2.f * x);
    return 1.f - 2.f * __builtin_amdgcn_rcpf(e + 1.f);
}
__device__ __forceinline__ float fast_sigmoid(float x){
    return __builtin_amdgcn_rcpf(1.f + __expf(-x));
}
__device__ __forceinline__ bf16x4 tanh4(f32x4 a){
    bf16x4 o;
    o[0] = (bf16)fast_tanh(a[0]);
    o[1] = (bf16)fast_tanh(a[1]);
    o[2] = (bf16)fast_tanh(a[2]);
    o[3] = (bf16)fast_tanh(a[3]);
    return o;
}
__device__ __forceinline__ f32x4 bias4(const float* b, int f){
    f32x4 r; r[0]=b[f]; r[1]=b[f+1]; r[2]=b[f+2]; r[3]=b[f+3]; return r;
}

__global__ __launch_bounds__(512, 2)
void vae_rnn(const float* __restrict__ data,
             const float* __restrict__ ug_w1, const float* __restrict__ ug_b1,
             const float* __restrict__ ug_w2, const float* __restrict__ ug_b2,
             const float* __restrict__ rg_w1, const float* __restrict__ rg_b1,
             const float* __restrict__ rg_w2, const float* __restrict__ rg_b2,
             const float* __restrict__ ns_w1, const float* __restrict__ ns_b1,
             const float* __restrict__ ns_w2, const float* __restrict__ ns_b2,
             float* __restrict__ out)
{
    __shared__ __align__(16) char h_lds [16 * HS];   // [y|s(->hc)|x] bf16
    __shared__ __align__(16) char t_lds [16 * HS];   // tanh(l1) [ug|rg] bf16
    __shared__ __align__(16) char tn_lds[16 * TS];   // tanh(l1) ns bf16
    __shared__ float u_lds[16][68];                  // u gate fp32

    const int tid  = threadIdx.x;
    const int w    = tid >> 6;
    const int lane = tid & 63;
    const int lq   = lane >> 4;
    const int lc   = lane & 15;          // batch row within tile
    const int row0 = blockIdx.x * 16;

    const bool UG = (w < 4);             // ug side / u-role / mean-role
    const int fA = w * 32;               // A feats (256 over 8 waves)
    const int fB = (w & 3) * 16;         // B gate feats (64 per role)
    const int fC = w * 16;               // C feats (128 over 8 waves)
    const int fD = w * 16;               // D feats (mean 0:64, std 64:128)

    const float* W1 = UG ? ug_w1 : rg_w1;
    const float* B1 = UG ? ug_b1 : rg_b1;
    const float* W2 = UG ? ug_w2 : rg_w2;
    const float* B2 = UG ? ug_b2 : rg_b2;

    // ---------------- persistent weight fragments ----------------
    bf16x8 wAy[8], wAx[8]; f32x4 bA[2];
    #pragma unroll
    for (int j = 0; j < 2; ++j){
        int n = (fA + j*16 + lc) & 127;
        bA[j] = bias4(B1, (fA + j*16 + lq*4) & 127);
        #pragma unroll
        for (int kt = 0; kt < 4; ++kt){
            bf16x8 fy, fx;
            #pragma unroll
            for (int e = 0; e < 8; ++e){
                fy[e] = (bf16)W1[(      kt*32 + lq*8 + e)*128 + n];
                fx[e] = (bf16)W1[(128 + kt*32 + lq*8 + e)*128 + n];
            }
            wAy[kt*2 + j] = fy; wAx[kt*2 + j] = fx;
        }
    }
    bf16x8 wB[4]; f32x4 bB = bias4(B2, fB + lq*4);
    {
        int n = fB + lc;
        #pragma unroll
        for (int kt = 0; kt < 4; ++kt){
            bf16x8 f;
            #pragma unroll
            for (int e = 0; e < 8; ++e) f[e] = (bf16)W2[(kt*32 + lq*8 + e)*64 + n];
            wB[kt] = f;
        }
    }
    bf16x8 wCh[4], wCx[4]; f32x4 bC = bias4(ns_b1, fC + lq*4);
    {
        int n = fC + lc;
        #pragma unroll
        for (int kt = 0; kt < 4; ++kt){
            bf16x8 fh, fx;
            #pragma unroll
            for (int e = 0; e < 8; ++e){
                fh[e] = (bf16)ns_w1[(      kt*32 + lq*8 + e)*128 + n];
                fx[e] = (bf16)ns_w1[(128 + kt*32 + lq*8 + e)*128 + n];
            }
            wCh[kt] = fh; wCx[kt] = fx;
        }
    }
    bf16x8 wD[4]; f32x4 bD = bias4(ns_b2, fD + lq*4);
    {
        int n = fD + lc;
        #pragma unroll
        for (int kt = 0; kt < 4; ++kt){
            bf16x8 f;
            #pragma unroll
            for (int e = 0; e < 8; ++e) f[e] = (bf16)ns_w2[(kt*32 + lq*8 + e)*128 + n];
            wD[kt] = f;
        }
    }

    // ---------------- LDS pointers (loop-invariant) ----------------
    const char* h_ys_rd = h_lds + lc*HS + lq*16;          // + kt*64 (y,s / hc)
    const char* h_x_rd  = h_lds + lc*HS + 256 + lq*16;    // + kt*64 (x)
    char*       t_wr    = t_lds + lc*HS + 2*(fA + lq*4);  // + j*32
    const char* t_rd    = t_lds + lc*HS + lq*16 + (UG ? 0 : 256);
    char*       tn_wr   = tn_lds + lc*TS + 2*(fC + lq*4);
    const char* tn_rd   = tn_lds + lc*TS + lq*16;         // + kt*64
    char*       h_st_wr = h_lds + lc*HS + 2*(fD + lq*4);  // y/s publish
    char*       ys_rw   = h_lds + lc*HS + 2*(fB + lq*4);  // r-wave rw; +128 s

    // x stage mapping: thread -> (row, 4 floats)
    const int xr = tid >> 5;             // 0..15
    const int xc = (tid & 31) << 2;      // 0..124
    const float* xsrc = data + (size_t)(row0 + xr) * (size_t)(NT * ND) + xc;
    char* x_wr = h_lds + xr*HS + 256 + 2*xc;

    // ---------------- prologue ----------------
    float4 xn = *(const float4*)(xsrc + ND);                 // x(1)
    *(bf16x4*)(h_lds + xr*HS + (tid & 31)*8) = (bf16x4){};   // zero y,s cols
    {
        float4 x0 = *(const float4*)xsrc;
        bf16x4 xb0 = { (bf16)x0.x, (bf16)x0.y, (bf16)x0.z, (bf16)x0.w };
        *(bf16x4*)x_wr = xb0;                                 // stage x(0)
    }
    BAR();
    f32x4 Ax0, Ax1, Cx;                  // carried x-partials (incl. bias)
    {
        bf16x8 x0f = *(const bf16x8*)(h_x_rd +   0);
        bf16x8 x1f = *(const bf16x8*)(h_x_rd +  64);
        bf16x8 x2f = *(const bf16x8*)(h_x_rd + 128);
        bf16x8 x3f = *(const bf16x8*)(h_x_rd + 192);
        Ax0 = bA[0]; Ax1 = bA[1]; Cx = bC;
        Ax0 = mfma16(wAx[0], x0f, Ax0);  Ax1 = mfma16(wAx[1], x0f, Ax1);
        Ax0 = mfma16(wAx[2], x1f, Ax0);  Ax1 = mfma16(wAx[3], x1f, Ax1);
        Ax0 = mfma16(wAx[4], x2f, Ax0);  Ax1 = mfma16(wAx[5], x2f, Ax1);
        Ax0 = mfma16(wAx[6], x3f, Ax0);  Ax1 = mfma16(wAx[7], x3f, Ax1);
        Cx  = mfma16(wCx[0], x0f, Cx);
        Cx  = mfma16(wCx[1], x1f, Cx);
        Cx  = mfma16(wCx[2], x2f, Cx);
        Cx  = mfma16(wCx[3], x3f, Cx);
    }
    BAR();   // x(0) frag reads complete before overwrite
    {
        bf16x4 xb1 = { (bf16)xn.x, (bf16)xn.y, (bf16)xn.z, (bf16)xn.w };
        *(bf16x4*)x_wr = xb1;                                 // stage x(1)
    }
    f32x4 st = {0.f,0.f,0.f,0.f};        // y-state (mean waves) / s-state
    f32x4 ug_reg = {0.f,0.f,0.f,0.f};
    f32x4 uu = {0.f,0.f,0.f,0.f};
    BAR();

    #pragma unroll 1
    for (int t = 0; t < NT; ++t){
        bf16x8 xf0, xf1, xf2, xf3;       // x(t+1) frags, consumed P2/P3
        bf16x4 yb, sb;                   // r-wave pre-read of y,s

        // ---- P1: A_ys(t) (4x 2-deep chains, acc = carried A_x(t)) ----
        {
            xf0 = *(const bf16x8*)(h_x_rd +   0);
            xf1 = *(const bf16x8*)(h_x_rd +  64);
            xf2 = *(const bf16x8*)(h_x_rd + 128);
            xf3 = *(const bf16x8*)(h_x_rd + 192);
            if (!UG){
                yb = *(const bf16x4*)(ys_rw);
                sb = *(const bf16x4*)(ys_rw + 128);
            }
            bf16x8 h0 = *(const bf16x8*)(h_ys_rd +   0);
            bf16x8 h1 = *(const bf16x8*)(h_ys_rd +  64);
            bf16x8 h2 = *(const bf16x8*)(h_ys_rd + 128);
            bf16x8 h3 = *(const bf16x8*)(h_ys_rd + 192);
            f32x4 a0a = Ax0, a1a = Ax1;
            f32x4 a0b = {0.f,0.f,0.f,0.f}, a1b = {0.f,0.f,0.f,0.f};
            a0a = mfma16(wAy[0], h0, a0a);  a1a = mfma16(wAy[1], h0, a1a);
            a0b = mfma16(wAy[2], h1, a0b);  a1b = mfma16(wAy[3], h1, a1b);
            a0a = mfma16(wAy[4], h2, a0a);  a1a = mfma16(wAy[5], h2, a1a);
            a0b = mfma16(wAy[6], h3, a0b);  a1b = mfma16(wAy[7], h3, a1b);
            f32x4 a0 = a0a + a0b, a1 = a1a + a1b;
            *(bf16x4*)(t_wr +  0) = tanh4(a0);
            *(bf16x4*)(t_wr + 32) = tanh4(a1);
        }
        // global prefetch x(t+2): in flight until P4's publish
        int t2 = (t + 2 < NT) ? (t + 2) : (NT - 1);
        xn = *(const float4*)(xsrc + (size_t)t2 * ND);
        BAR();

        // ---- P2: B(t); A_x(t+1) on xf in shadow; gates; hc in place ----
        {
            f32x4 b0 = bB, b1 = {0.f,0.f,0.f,0.f};
            bf16x8 t0 = *(const bf16x8*)(t_rd +   0);
            bf16x8 t1 = *(const bf16x8*)(t_rd +  64);
            bf16x8 t2v = *(const bf16x8*)(t_rd + 128);
            bf16x8 t3 = *(const bf16x8*)(t_rd + 192);
            b0 = mfma16(wB[0], t0, b0);
            b1 = mfma16(wB[1], t1, b1);
            b0 = mfma16(wB[2], t2v, b0);
            b1 = mfma16(wB[3], t3, b1);
            // A_x(t+1), 4x 2-deep chains
            f32x4 ax0a = bA[0], ax1a = bA[1];
            f32x4 ax0b = {0.f,0.f,0.f,0.f}, ax1b = {0.f,0.f,0.f,0.f};
            ax0a = mfma16(wAx[0], xf0, ax0a);  ax1a = mfma16(wAx[1], xf0, ax1a);
            ax0b = mfma16(wAx[2], xf1, ax0b);  ax1b = mfma16(wAx[3], xf1, ax1b);
            ax0a = mfma16(wAx[4], xf2, ax0a);  ax1a = mfma16(wAx[5], xf2, ax1a);
            ax0b = mfma16(wAx[6], xf3, ax0b);  ax1b = mfma16(wAx[7], xf3, ax1b);
            Ax0 = ax0a + ax0b; Ax1 = ax1a + ax1b;
            f32x4 bs = b0 + b1;
            float g0 = fast_sigmoid(bs[0]);
            float g1 = fast_sigmoid(bs[1]);
            float g2 = fast_sigmoid(bs[2]);
            float g3 = fast_sigmoid(bs[3]);
            if (UG){
                ug_reg[0] = g0; ug_reg[1] = g1; ug_reg[2] = g2; ug_reg[3] = g3;
                *(f32x4*)&u_lds[lc][fB + lq*4] = ug_reg;
            } else {
                bf16x4 hy = { (bf16)((float)yb[0]*g0), (bf16)((float)yb[1]*g1),
                              (bf16)((float)yb[2]*g2), (bf16)((float)yb[3]*g3) };
                bf16x4 hs = { (bf16)((float)sb[0]*g0), (bf16)((float)sb[1]*g1),
                              (bf16)((float)sb[2]*g2), (bf16)((float)sb[3]*g3) };
                *(bf16x4*)(ys_rw)       = hy;     // hc y*r over y cols
                *(bf16x4*)(ys_rw + 128) = hs;     // hc s*r over s cols
            }
        }
        BAR();

        // ---- P3: C_hc(t) (acc = carried C_x(t)); C_x(t+1); u pre-read ----
        {
            if (!UG) uu = *(const f32x4*)&u_lds[lc][fB + lq*4];
            bf16x8 h0 = *(const bf16x8*)(h_ys_rd +   0);
            bf16x8 h1 = *(const bf16x8*)(h_ys_rd +  64);
            bf16x8 h2 = *(const bf16x8*)(h_ys_rd + 128);
            bf16x8 h3 = *(const bf16x8*)(h_ys_rd + 192);
            f32x4 c0 = Cx, c1 = {0.f,0.f,0.f,0.f};
            c0 = mfma16(wCh[0], h0, c0);
            c1 = mfma16(wCh[1], h1, c1);
            c0 = mfma16(wCh[2], h2, c0);
            c1 = mfma16(wCh[3], h3, c1);
            // C_x(t+1), 2x 2-deep
            f32x4 cxa = bC, cxb = {0.f,0.f,0.f,0.f};
            cxa = mfma16(wCx[0], xf0, cxa);
            cxb = mfma16(wCx[1], xf1, cxb);
            cxa = mfma16(wCx[2], xf2, cxa);
            cxb = mfma16(wCx[3], xf3, cxb);
            Cx = cxa + cxb;
            f32x4 cs = c0 + c1;
            *(bf16x4*)tn_wr = tanh4(cs);
        }
        BAR();

        // ---- P4: D(t); EMA; publish y,s bf16; publish x(t+2) ----
        {
            bf16x8 n0 = *(const bf16x8*)(tn_rd +   0);
            bf16x8 n1 = *(const bf16x8*)(tn_rd +  64);
            bf16x8 n2 = *(const bf16x8*)(tn_rd + 128);
            bf16x8 n3 = *(const bf16x8*)(tn_rd + 192);
            f32x4 d0 = bD, d1 = {0.f,0.f,0.f,0.f};
            d0 = mfma16(wD[0], n0, d0);
            d1 = mfma16(wD[1], n1, d1);
            d0 = mfma16(wD[2], n2, d0);
            d1 = mfma16(wD[3], n3, d1);
            f32x4 ds = d0 + d1;
            f32x4 u4 = UG ? ug_reg : uu;
            #pragma unroll
            for (int i = 0; i < 4; ++i){
                float v = UG ? ds[i] : fabsf(ds[i]);
                st[i] = fmaf(u4[i], st[i] - v, v);
            }
            bf16x4 hn = { (bf16)st[0], (bf16)st[1], (bf16)st[2], (bf16)st[3] };
            *(bf16x4*)h_st_wr = hn;
            // publish x(t+2) (xn issued in P1 -> 3 phases of cover)
            bf16x4 xb = { (bf16)xn.x, (bf16)xn.y, (bf16)xn.z, (bf16)xn.w };
            *(bf16x4*)x_wr = xb;
        }
        BAR();
    }

    // ---------------- output: yT (4096x64) then sT (4096x64), fp32 ----------
    {
        size_t gr = (size_t)(row0 + lc);
        float4 v = make_float4(st[0], st[1], st[2], st[3]);
        if (UG) *(float4*)&out[gr*64 + fD + lq*4] = v;
        else    *(float4*)&out[(size_t)NB*64 + gr*64 + (fD - 64) + lq*4] = v;
    }
}

extern "C" void kernel_launch(void* const* d_in, const int* in_sizes, int n_in,
                              void* d_out, int out_size, void* d_ws, size_t ws_size,
                              hipStream_t stream) {
    const float* data  = (const float*)d_in[0];
    // d_in[1] = time_steps — unused by the reference computation
    const float* ug_w1 = (const float*)d_in[2];
    const float* ug_b1 = (const float*)d_in[3];
    const float* ug_w2 = (const float*)d_in[4];
    const float* ug_b2 = (const float*)d_in[5];
    const float* rg_w1 = (const float*)d_in[6];
    const float* rg_b1 = (const float*)d_in[7];
    const float* rg_w2 = (const float*)d_in[8];
    const float* rg_b2 = (const float*)d_in[9];
    const float* ns_w1 = (const float*)d_in[10];
    const float* ns_b1 = (const float*)d_in[11];
    const float* ns_w2 = (const float*)d_in[12];
    const float* ns_b2 = (const float*)d_in[13];

    hipLaunchKernelGGL(vae_rnn, dim3(NB/16), dim3(512), 0, stream,
                       data, ug_w1, ug_b1, ug_w2, ug_b2,
                       rg_w1, rg_b1, rg_w2, rg_b2,
                       ns_w1, ns_b1, ns_w2, ns_b2,
                       (float*)d_out);
}

// Round 11
// 339.331 us; speedup vs baseline: 1.5238x; 1.0053x over previous
//
#include <hip/hip_runtime.h>
#include <hip/hip_bf16.h>

// VAE_RNN: B=4096, T=200, D=128, L=64, H=128, CIN=2L+D=256
// Persistent-block RNN, 256 blocks x 512 threads (8 waves), 16 rows/block.
// Weights register-resident. R11 = R8 (324us, best) + minimal deltas:
//  - x publish/prefetch owned by UG waves (tid<256) as bf16x8 / 2x float4
//  - r-waves pre-read y,s (8B) in P1 (consumed by P2's hc)
//  - std waves pre-read u in P3 (under C's MFMA shadow); P4 u is register-only
// Phase structure (4 lgkm-only barriers; x-partials carried in accumulators):
//  P1: A_ys(t) [8 MFMA, acc=carried Ax] -> tanh -> t_lds
//      UG: publish x(t+1), prefetch x(t+2) | r: pre-read y,s
//  P2: B(t) [4 MFMA] -> sigmoid; xf reads + A_x(t+1) [8 MFMA] in shadow;
//      u-waves: u -> regs+u_lds | r-waves: hc = y*r,s*r in place
//  P3: C_hc(t) [4 MFMA, acc=carried Cx] -> tanh -> tn_lds; C_x(t+1) [4 MFMA];
//      std waves pre-read u_lds
//  P4: D(t) [4 MFMA] -> EMA (fp32 regs) -> publish y,s bf16

#define NB 4096
#define NT 200
#define ND 128
#define HS 528      // h/t row stride bytes
#define TS 272      // tn row stride bytes

typedef __bf16 bf16;
typedef __attribute__((ext_vector_type(8))) __bf16 bf16x8;
typedef __attribute__((ext_vector_type(4))) __bf16 bf16x4;
typedef __attribute__((ext_vector_type(4))) float f32x4;

#define BAR() asm volatile("s_waitcnt lgkmcnt(0)\n\ts_barrier" ::: "memory")

__device__ __forceinline__ f32x4 mfma16(bf16x8 a, bf16x8 b, f32x4 c){
    return __builtin_amdgcn_mfma_f32_16x16x32_bf16(a, b, c, 0, 0, 0);
}
// inf-safe, branch-free
__device__ __forceinline__ float fast_tanh(float x){
    float e = __expf(2.f * x);
    return 1.f - 2.f * __builtin_amdgcn_rcpf(e + 1.f);
}
__device__ __forceinline__ float fast_sigmoid(float x){
    return __builtin_amdgcn_rcpf(1.f + __expf(-x));
}
__device__ __forceinline__ bf16x4 tanh4(f32x4 a){
    bf16x4 o;
    o[0] = (bf16)fast_tanh(a[0]);
    o[1] = (bf16)fast_tanh(a[1]);
    o[2] = (bf16)fast_tanh(a[2]);
    o[3] = (bf16)fast_tanh(a[3]);
    return o;
}
__device__ __forceinline__ f32x4 bias4(const float* b, int f){
    f32x4 r; r[0]=b[f]; r[1]=b[f+1]; r[2]=b[f+2]; r[3]=b[f+3]; return r;
}

__global__ __launch_bounds__(512, 2)
void vae_rnn(const float* __restrict__ data,
             const float* __restrict__ ug_w1, const float* __restrict__ ug_b1,
             const float* __restrict__ ug_w2, const float* __restrict__ ug_b2,
             const float* __restrict__ rg_w1, const float* __restrict__ rg_b1,
             const float* __restrict__ rg_w2, const float* __restrict__ rg_b2,
             const float* __restrict__ ns_w1, const float* __restrict__ ns_b1,
             const float* __restrict__ ns_w2, const float* __restrict__ ns_b2,
             float* __restrict__ out)
{
    __shared__ __align__(16) char h_lds [16 * HS];   // [y|s(->hc)|x] bf16
    __shared__ __align__(16) char t_lds [16 * HS];   // tanh(l1) [ug|rg] bf16
    __shared__ __align__(16) char tn_lds[16 * TS];   // tanh(l1) ns bf16
    __shared__ float u_lds[16][68];                  // u gate fp32

    const int tid  = threadIdx.x;
    const int w    = tid >> 6;
    const int lane = tid & 63;
    const int lq   = lane >> 4;
    const int lc   = lane & 15;          // batch row within tile
    const int row0 = blockIdx.x * 16;

    const bool UG = (w < 4);             // ug side / u-role / mean-role / x-owner
    const int fA = w * 32;               // A feats (256 over 8 waves)
    const int fB = (w & 3) * 16;         // B gate feats (64 per role)
    const int fC = w * 16;               // C feats (128 over 8 waves)
    const int fD = w * 16;               // D feats (mean 0:64, std 64:128)

    const float* W1 = UG ? ug_w1 : rg_w1;
    const float* B1 = UG ? ug_b1 : rg_b1;
    const float* W2 = UG ? ug_w2 : rg_w2;
    const float* B2 = UG ? ug_b2 : rg_b2;

    // ---------------- persistent weight fragments ----------------
    bf16x8 wAy[8], wAx[8]; f32x4 bA[2];
    #pragma unroll
    for (int j = 0; j < 2; ++j){
        int n = (fA + j*16 + lc) & 127;
        bA[j] = bias4(B1, (fA + j*16 + lq*4) & 127);
        #pragma unroll
        for (int kt = 0; kt < 4; ++kt){
            bf16x8 fy, fx;
            #pragma unroll
            for (int e = 0; e < 8; ++e){
                fy[e] = (bf16)W1[(      kt*32 + lq*8 + e)*128 + n];
                fx[e] = (bf16)W1[(128 + kt*32 + lq*8 + e)*128 + n];
            }
            wAy[kt*2 + j] = fy; wAx[kt*2 + j] = fx;
        }
    }
    bf16x8 wB[4]; f32x4 bB = bias4(B2, fB + lq*4);
    {
        int n = fB + lc;
        #pragma unroll
        for (int kt = 0; kt < 4; ++kt){
            bf16x8 f;
            #pragma unroll
            for (int e = 0; e < 8; ++e) f[e] = (bf16)W2[(kt*32 + lq*8 + e)*64 + n];
            wB[kt] = f;
        }
    }
    bf16x8 wCh[4], wCx[4]; f32x4 bC = bias4(ns_b1, fC + lq*4);
    {
        int n = fC + lc;
        #pragma unroll
        for (int kt = 0; kt < 4; ++kt){
            bf16x8 fh, fx;
            #pragma unroll
            for (int e = 0; e < 8; ++e){
                fh[e] = (bf16)ns_w1[(      kt*32 + lq*8 + e)*128 + n];
                fx[e] = (bf16)ns_w1[(128 + kt*32 + lq*8 + e)*128 + n];
            }
            wCh[kt] = fh; wCx[kt] = fx;
        }
    }
    bf16x8 wD[4]; f32x4 bD = bias4(ns_b2, fD + lq*4);
    {
        int n = fD + lc;
        #pragma unroll
        for (int kt = 0; kt < 4; ++kt){
            bf16x8 f;
            #pragma unroll
            for (int e = 0; e < 8; ++e) f[e] = (bf16)ns_w2[(kt*32 + lq*8 + e)*128 + n];
            wD[kt] = f;
        }
    }

    // ---------------- LDS pointers (loop-invariant) ----------------
    const char* h_ys_rd = h_lds + lc*HS + lq*16;          // + kt*64 (y,s / hc)
    const char* h_x_rd  = h_lds + lc*HS + 256 + lq*16;    // + kt*64 (x)
    char*       t_wr    = t_lds + lc*HS + 2*(fA + lq*4);  // + j*32
    const char* t_rd    = t_lds + lc*HS + lq*16 + (UG ? 0 : 256);
    char*       tn_wr   = tn_lds + lc*TS + 2*(fC + lq*4);
    const char* tn_rd   = tn_lds + lc*TS + lq*16;         // + kt*64
    char*       h_st_wr = h_lds + lc*HS + 2*(fD + lq*4);  // y/s publish
    char*       ys_rw   = h_lds + lc*HS + 2*(fB + lq*4);  // r-wave rw; +128 s

    // x stage mapping (UG waves, tid<256): row xr, 8-float chunk
    const int xr  = tid >> 4;            // 0..15
    const int xc8 = (tid & 15) * 8;      // float offset 0..120
    const float* xsrc = data + (size_t)(row0 + (xr & 15)) * (size_t)(NT * ND) + xc8;
    char* x_wr = h_lds + (xr & 15)*HS + 256 + 2*xc8;

    // ---------------- prologue ----------------
    *(bf16x4*)(h_lds + (tid >> 5)*HS + (tid & 31)*8) = (bf16x4){};  // zero y,s
    float4 xn0, xn1;
    if (UG){
        float4 a0 = *(const float4*)xsrc;
        float4 a1 = *(const float4*)(xsrc + 4);
        bf16x8 xv = { (bf16)a0.x,(bf16)a0.y,(bf16)a0.z,(bf16)a0.w,
                      (bf16)a1.x,(bf16)a1.y,(bf16)a1.z,(bf16)a1.w };
        *(bf16x8*)x_wr = xv;                                 // stage x(0)
        xn0 = *(const float4*)(xsrc + ND);                   // x(1)
        xn1 = *(const float4*)(xsrc + ND + 4);
    }
    BAR();
    f32x4 Ax0, Ax1, Cx;                  // carried x-partials (incl. bias)
    {
        bf16x8 x0f = *(const bf16x8*)(h_x_rd +   0);
        bf16x8 x1f = *(const bf16x8*)(h_x_rd +  64);
        bf16x8 x2f = *(const bf16x8*)(h_x_rd + 128);
        bf16x8 x3f = *(const bf16x8*)(h_x_rd + 192);
        Ax0 = bA[0]; Ax1 = bA[1]; Cx = bC;
        Ax0 = mfma16(wAx[0], x0f, Ax0);  Ax1 = mfma16(wAx[1], x0f, Ax1);
        Ax0 = mfma16(wAx[2], x1f, Ax0);  Ax1 = mfma16(wAx[3], x1f, Ax1);
        Ax0 = mfma16(wAx[4], x2f, Ax0);  Ax1 = mfma16(wAx[5], x2f, Ax1);
        Ax0 = mfma16(wAx[6], x3f, Ax0);  Ax1 = mfma16(wAx[7], x3f, Ax1);
        Cx  = mfma16(wCx[0], x0f, Cx);
        Cx  = mfma16(wCx[1], x1f, Cx);
        Cx  = mfma16(wCx[2], x2f, Cx);
        Cx  = mfma16(wCx[3], x3f, Cx);
    }
    f32x4 st = {0.f,0.f,0.f,0.f};        // y-state (mean waves) / s-state
    f32x4 ug_reg = {0.f,0.f,0.f,0.f};
    f32x4 uu = {0.f,0.f,0.f,0.f};
    BAR();                               // x(0) frag reads done before overwrite

    #pragma unroll 1
    for (int t = 0; t < NT; ++t){
        bf16x4 yb, sb;                   // r-wave pre-read of y,s (for P2 hc)

        // ---- P1: A_ys(t) (acc = carried A_x(t)) -> tanh -> t_lds ----
        {
            f32x4 a0 = Ax0, a1 = Ax1;
            #pragma unroll
            for (int kt = 0; kt < 4; ++kt){
                bf16x8 hv = *(const bf16x8*)(h_ys_rd + kt*64);
                a0 = mfma16(wAy[kt*2+0], hv, a0);
                a1 = mfma16(wAy[kt*2+1], hv, a1);
            }
            *(bf16x4*)(t_wr +  0) = tanh4(a0);
            *(bf16x4*)(t_wr + 32) = tanh4(a1);
            if (UG){
                // publish x(t+1); prefetch x(t+2) (in flight across barriers)
                bf16x8 xv = { (bf16)xn0.x,(bf16)xn0.y,(bf16)xn0.z,(bf16)xn0.w,
                              (bf16)xn1.x,(bf16)xn1.y,(bf16)xn1.z,(bf16)xn1.w };
                *(bf16x8*)x_wr = xv;
                int t2 = (t + 2 < NT) ? (t + 2) : (NT - 1);
                xn0 = *(const float4*)(xsrc + (size_t)t2*ND);
                xn1 = *(const float4*)(xsrc + (size_t)t2*ND + 4);
            } else {
                yb = *(const bf16x4*)(ys_rw);
                sb = *(const bf16x4*)(ys_rw + 128);
            }
        }
        BAR();

        // ---- P2: B(t); xf reads + A_x(t+1) in shadow; gates; hc in place ----
        bf16x8 xf0, xf1, xf2, xf3;
        {
            f32x4 b0 = bB, b1 = {0.f,0.f,0.f,0.f};
            #pragma unroll
            for (int kt = 0; kt < 4; ++kt){
                bf16x8 tv = *(const bf16x8*)(t_rd + kt*64);
                if (kt & 1) b1 = mfma16(wB[kt], tv, b1);
                else        b0 = mfma16(wB[kt], tv, b0);
            }
            xf0 = *(const bf16x8*)(h_x_rd +   0);
            xf1 = *(const bf16x8*)(h_x_rd +  64);
            xf2 = *(const bf16x8*)(h_x_rd + 128);
            xf3 = *(const bf16x8*)(h_x_rd + 192);
            f32x4 ax0 = bA[0], ax1 = bA[1];
            ax0 = mfma16(wAx[0], xf0, ax0);  ax1 = mfma16(wAx[1], xf0, ax1);
            ax0 = mfma16(wAx[2], xf1, ax0);  ax1 = mfma16(wAx[3], xf1, ax1);
            ax0 = mfma16(wAx[4], xf2, ax0);  ax1 = mfma16(wAx[5], xf2, ax1);
            ax0 = mfma16(wAx[6], xf3, ax0);  ax1 = mfma16(wAx[7], xf3, ax1);
            Ax0 = ax0; Ax1 = ax1;
            f32x4 bs = b0 + b1;
            float g0 = fast_sigmoid(bs[0]);
            float g1 = fast_sigmoid(bs[1]);
            float g2 = fast_sigmoid(bs[2]);
            float g3 = fast_sigmoid(bs[3]);
            if (UG){
                ug_reg[0] = g0; ug_reg[1] = g1; ug_reg[2] = g2; ug_reg[3] = g3;
                *(f32x4*)&u_lds[lc][fB + lq*4] = ug_reg;
            } else {
                bf16x4 hy = { (bf16)((float)yb[0]*g0), (bf16)((float)yb[1]*g1),
                              (bf16)((float)yb[2]*g2), (bf16)((float)yb[3]*g3) };
                bf16x4 hs = { (bf16)((float)sb[0]*g0), (bf16)((float)sb[1]*g1),
                              (bf16)((float)sb[2]*g2), (bf16)((float)sb[3]*g3) };
                *(bf16x4*)(ys_rw)       = hy;     // hc y*r over y cols
                *(bf16x4*)(ys_rw + 128) = hs;     // hc s*r over s cols
            }
        }
        BAR();

        // ---- P3: C_hc(t) (acc = carried C_x(t)); C_x(t+1); u pre-read ----
        {
            if (!UG) uu = *(const f32x4*)&u_lds[lc][fB + lq*4];
            f32x4 c0 = Cx, c1 = {0.f,0.f,0.f,0.f};
            #pragma unroll
            for (int kt = 0; kt < 4; ++kt){
                bf16x8 hv = *(const bf16x8*)(h_ys_rd + kt*64);
                if (kt & 1) c1 = mfma16(wCh[kt], hv, c1);
                else        c0 = mfma16(wCh[kt], hv, c0);
            }
            f32x4 cx = bC;
            cx = mfma16(wCx[0], xf0, cx);
            cx = mfma16(wCx[1], xf1, cx);
            cx = mfma16(wCx[2], xf2, cx);
            cx = mfma16(wCx[3], xf3, cx);
            Cx = cx;
            f32x4 cs = c0 + c1;
            *(bf16x4*)tn_wr = tanh4(cs);
        }
        BAR();

        // ---- P4: D(t); EMA (u register-only); publish y,s bf16 ----
        {
            f32x4 d0 = bD, d1 = {0.f,0.f,0.f,0.f};
            #pragma unroll
            for (int kt = 0; kt < 4; ++kt){
                bf16x8 tv = *(const bf16x8*)(tn_rd + kt*64);
                if (kt & 1) d1 = mfma16(wD[kt], tv, d1);
                else        d0 = mfma16(wD[kt], tv, d0);
            }
            f32x4 ds = d0 + d1;
            f32x4 u4 = UG ? ug_reg : uu;
            #pragma unroll
            for (int i = 0; i < 4; ++i){
                float v = UG ? ds[i] : fabsf(ds[i]);
                st[i] = fmaf(u4[i], st[i] - v, v);
            }
            bf16x4 hn = { (bf16)st[0], (bf16)st[1], (bf16)st[2], (bf16)st[3] };
            *(bf16x4*)h_st_wr = hn;
        }
        BAR();
    }

    // ---------------- output: yT (4096x64) then sT (4096x64), fp32 ----------
    {
        size_t gr = (size_t)(row0 + lc);
        float4 v = make_float4(st[0], st[1], st[2], st[3]);
        if (UG) *(float4*)&out[gr*64 + fD + lq*4] = v;
        else    *(float4*)&out[(size_t)NB*64 + gr*64 + (fD - 64) + lq*4] = v;
    }
}

extern "C" void kernel_launch(void* const* d_in, const int* in_sizes, int n_in,
                              void* d_out, int out_size, void* d_ws, size_t ws_size,
                              hipStream_t stream) {
    const float* data  = (const float*)d_in[0];
    // d_in[1] = time_steps — unused by the reference computation
    const float* ug_w1 = (const float*)d_in[2];
    const float* ug_b1 = (const float*)d_in[3];
    const float* ug_w2 = (const float*)d_in[4];
    const float* ug_b2 = (const float*)d_in[5];
    const float* rg_w1 = (const float*)d_in[6];
    const float* rg_b1 = (const float*)d_in[7];
    const float* rg_w2 = (const float*)d_in[8];
    const float* rg_b2 = (const float*)d_in[9];
    const float* ns_w1 = (const float*)d_in[10];
    const float* ns_b1 = (const float*)d_in[11];
    const float* ns_w2 = (const float*)d_in[12];
    const float* ns_b2 = (const float*)d_in[13];

    hipLaunchKernelGGL(vae_rnn, dim3(NB/16), dim3(512), 0, stream,
                       data, ug_w1, ug_b1, ug_w2, ug_b2,
                       rg_w1, rg_b1, rg_w2, rg_b2,
                       ns_w1, ns_b1, ns_w2, ns_b2,
                       (float*)d_out);
}

// Round 12
// 332.779 us; speedup vs baseline: 1.5538x; 1.0197x over previous
//
#include <hip/hip_runtime.h>
#include <hip/hip_bf16.h>

// VAE_RNN: B=4096, T=200, D=128, L=64, H=128, CIN=2L+D=256
// Persistent-block RNN, 256 blocks x 512 threads (8 symmetric waves),
// 16 rows/block, 200 steps. Weights register-resident.
// R12 = R8 (324us, best) + (a) s_setprio(1) around each MFMA cluster,
// (b) u_lds pre-read moved P4 -> P3 (under C's MFMA shadow). Nothing added
// to P1 (R10/R11 showed P1 is the ring-critical phase; P2/P3 shadows are free).
//   P1: A_ys(t) [8 MFMA, acc=carried Ax] -> tanh -> t_lds
//       + publish x(t+1), prefetch x(t+2)
//   P2: B(t) [4 MFMA] -> sigmoid; xf reads + A_x(t+1) [8 MFMA] in shadow;
//       u-waves: u -> regs+u_lds | r-waves: hc = y*r, s*r in place
//   P3: C_hc(t) [4 MFMA, acc=carried Cx] -> tanh -> tn_lds; C_x(t+1) [4 MFMA];
//       std waves pre-read u_lds
//   P4: D(t) [4 MFMA] -> EMA (fp32 regs, u register-only) -> publish y,s bf16
// 4 lgkm-only barriers/step; x-partials carried in accumulator registers.

#define NB 4096
#define NT 200
#define ND 128
#define HS 528      // h/t row stride bytes
#define TS 272      // tn row stride bytes

typedef __bf16 bf16;
typedef __attribute__((ext_vector_type(8))) __bf16 bf16x8;
typedef __attribute__((ext_vector_type(4))) __bf16 bf16x4;
typedef __attribute__((ext_vector_type(4))) float f32x4;

#define BAR() asm volatile("s_waitcnt lgkmcnt(0)\n\ts_barrier" ::: "memory")
#define PRIO1() __builtin_amdgcn_s_setprio(1)
#define PRIO0() __builtin_amdgcn_s_setprio(0)

__device__ __forceinline__ f32x4 mfma16(bf16x8 a, bf16x8 b, f32x4 c){
    return __builtin_amdgcn_mfma_f32_16x16x32_bf16(a, b, c, 0, 0, 0);
}
// inf-safe, branch-free
__device__ __forceinline__ float fast_tanh(float x){
    float e = __expf(2.f * x);
    return 1.f - 2.f * __builtin_amdgcn_rcpf(e + 1.f);
}
__device__ __forceinline__ float fast_sigmoid(float x){
    return __builtin_amdgcn_rcpf(1.f + __expf(-x));
}
__device__ __forceinline__ bf16x4 tanh4(f32x4 a){
    bf16x4 o;
    o[0] = (bf16)fast_tanh(a[0]);
    o[1] = (bf16)fast_tanh(a[1]);
    o[2] = (bf16)fast_tanh(a[2]);
    o[3] = (bf16)fast_tanh(a[3]);
    return o;
}
__device__ __forceinline__ f32x4 bias4(const float* b, int f){
    f32x4 r; r[0]=b[f]; r[1]=b[f+1]; r[2]=b[f+2]; r[3]=b[f+3]; return r;
}

__global__ __launch_bounds__(512, 2)
void vae_rnn(const float* __restrict__ data,
             const float* __restrict__ ug_w1, const float* __restrict__ ug_b1,
             const float* __restrict__ ug_w2, const float* __restrict__ ug_b2,
             const float* __restrict__ rg_w1, const float* __restrict__ rg_b1,
             const float* __restrict__ rg_w2, const float* __restrict__ rg_b2,
             const float* __restrict__ ns_w1, const float* __restrict__ ns_b1,
             const float* __restrict__ ns_w2, const float* __restrict__ ns_b2,
             float* __restrict__ out)
{
    __shared__ __align__(16) char h_lds [16 * HS];   // [y|s(->hc)|x] bf16
    __shared__ __align__(16) char t_lds [16 * HS];   // tanh(l1) [ug|rg] bf16
    __shared__ __align__(16) char tn_lds[16 * TS];   // tanh(l1) ns bf16
    __shared__ float u_lds[16][68];                  // u gate fp32

    const int tid  = threadIdx.x;
    const int w    = tid >> 6;
    const int lane = tid & 63;
    const int lq   = lane >> 4;
    const int lc   = lane & 15;          // batch row within tile
    const int row0 = blockIdx.x * 16;

    const bool UG = (w < 4);             // ug side / u-role / mean-role
    const int fA = w * 32;               // A feats (256 over 8 waves)
    const int fB = (w & 3) * 16;         // B gate feats (64 per role)
    const int fC = w * 16;               // C feats (128 over 8 waves)
    const int fD = w * 16;               // D feats (mean 0:64, std 64:128)

    const float* W1 = UG ? ug_w1 : rg_w1;
    const float* B1 = UG ? ug_b1 : rg_b1;
    const float* W2 = UG ? ug_w2 : rg_w2;
    const float* B2 = UG ? ug_b2 : rg_b2;

    // ---------------- persistent weight fragments ----------------
    bf16x8 wAy[8], wAx[8]; f32x4 bA[2];
    #pragma unroll
    for (int j = 0; j < 2; ++j){
        int n = (fA + j*16 + lc) & 127;
        bA[j] = bias4(B1, (fA + j*16 + lq*4) & 127);
        #pragma unroll
        for (int kt = 0; kt < 4; ++kt){
            bf16x8 fy, fx;
            #pragma unroll
            for (int e = 0; e < 8; ++e){
                fy[e] = (bf16)W1[(      kt*32 + lq*8 + e)*128 + n];
                fx[e] = (bf16)W1[(128 + kt*32 + lq*8 + e)*128 + n];
            }
            wAy[kt*2 + j] = fy; wAx[kt*2 + j] = fx;
        }
    }
    bf16x8 wB[4]; f32x4 bB = bias4(B2, fB + lq*4);
    {
        int n = fB + lc;
        #pragma unroll
        for (int kt = 0; kt < 4; ++kt){
            bf16x8 f;
            #pragma unroll
            for (int e = 0; e < 8; ++e) f[e] = (bf16)W2[(kt*32 + lq*8 + e)*64 + n];
            wB[kt] = f;
        }
    }
    bf16x8 wCh[4], wCx[4]; f32x4 bC = bias4(ns_b1, fC + lq*4);
    {
        int n = fC + lc;
        #pragma unroll
        for (int kt = 0; kt < 4; ++kt){
            bf16x8 fh, fx;
            #pragma unroll
            for (int e = 0; e < 8; ++e){
                fh[e] = (bf16)ns_w1[(      kt*32 + lq*8 + e)*128 + n];
                fx[e] = (bf16)ns_w1[(128 + kt*32 + lq*8 + e)*128 + n];
            }
            wCh[kt] = fh; wCx[kt] = fx;
        }
    }
    bf16x8 wD[4]; f32x4 bD = bias4(ns_b2, fD + lq*4);
    {
        int n = fD + lc;
        #pragma unroll
        for (int kt = 0; kt < 4; ++kt){
            bf16x8 f;
            #pragma unroll
            for (int e = 0; e < 8; ++e) f[e] = (bf16)ns_w2[(kt*32 + lq*8 + e)*128 + n];
            wD[kt] = f;
        }
    }

    // ---------------- LDS pointers (loop-invariant) ----------------
    const char* h_ys_rd = h_lds + lc*HS + lq*16;          // + kt*64 (y,s / hc)
    const char* h_x_rd  = h_lds + lc*HS + 256 + lq*16;    // + kt*64 (x)
    char*       t_wr    = t_lds + lc*HS + 2*(fA + lq*4);  // + j*32
    const char* t_rd    = t_lds + lc*HS + lq*16 + (UG ? 0 : 256);
    char*       tn_wr   = tn_lds + lc*TS + 2*(fC + lq*4);
    const char* tn_rd   = tn_lds + lc*TS + lq*16;         // + kt*64
    char*       h_st_wr = h_lds + lc*HS + 2*(fD + lq*4);  // y/s publish
    char*       ys_rw   = h_lds + lc*HS + 2*(fB + lq*4);  // r-wave rw; +128 s

    // x stage mapping: thread -> (row, 4 floats)
    const int xr = tid >> 5;             // 0..15
    const int xc = (tid & 31) << 2;      // 0..124
    const float* xsrc = data + (size_t)(row0 + xr) * (size_t)(NT * ND) + xc;
    char* x_wr = h_lds + xr*HS + 256 + 2*xc;

    // ---------------- prologue ----------------
    *(bf16x4*)(h_lds + xr*HS + (tid & 31)*8) = (bf16x4){};   // zero y,s cols
    {
        float4 x0 = *(const float4*)xsrc;
        bf16x4 xb0 = { (bf16)x0.x, (bf16)x0.y, (bf16)x0.z, (bf16)x0.w };
        *(bf16x4*)x_wr = xb0;                                 // stage x(0)
    }
    BAR();
    f32x4 Ax0, Ax1, Cx;                  // carried x-partials (incl. bias)
    {
        bf16x8 x0f = *(const bf16x8*)(h_x_rd +   0);
        bf16x8 x1f = *(const bf16x8*)(h_x_rd +  64);
        bf16x8 x2f = *(const bf16x8*)(h_x_rd + 128);
        bf16x8 x3f = *(const bf16x8*)(h_x_rd + 192);
        Ax0 = bA[0]; Ax1 = bA[1]; Cx = bC;
        Ax0 = mfma16(wAx[0], x0f, Ax0);  Ax1 = mfma16(wAx[1], x0f, Ax1);
        Ax0 = mfma16(wAx[2], x1f, Ax0);  Ax1 = mfma16(wAx[3], x1f, Ax1);
        Ax0 = mfma16(wAx[4], x2f, Ax0);  Ax1 = mfma16(wAx[5], x2f, Ax1);
        Ax0 = mfma16(wAx[6], x3f, Ax0);  Ax1 = mfma16(wAx[7], x3f, Ax1);
        Cx  = mfma16(wCx[0], x0f, Cx);
        Cx  = mfma16(wCx[1], x1f, Cx);
        Cx  = mfma16(wCx[2], x2f, Cx);
        Cx  = mfma16(wCx[3], x3f, Cx);
    }
    float4 xn = *(const float4*)(xsrc + ND);   // x(1) for first P1 publish
    f32x4 st = {0.f,0.f,0.f,0.f};              // y-state (mean) / s-state (std)
    f32x4 ug_reg = {0.f,0.f,0.f,0.f};
    f32x4 uu = {0.f,0.f,0.f,0.f};
    bf16x8 xf0, xf1, xf2, xf3;                 // x frags cached P2 -> P3
    BAR();   // x(0) frag reads complete before first P1's x(1) publish

    #pragma unroll 1
    for (int t = 0; t < NT; ++t){
        // ---- P1: A_ys(t), acc = carried A_x(t); publish x(t+1); prefetch ----
        {
            f32x4 a0 = Ax0, a1 = Ax1;
            PRIO1();
            #pragma unroll
            for (int kt = 0; kt < 4; ++kt){
                bf16x8 hv = *(const bf16x8*)(h_ys_rd + kt*64);
                a0 = mfma16(wAy[kt*2+0], hv, a0);
                a1 = mfma16(wAy[kt*2+1], hv, a1);
            }
            PRIO0();
            *(bf16x4*)(t_wr +  0) = tanh4(a0);
            *(bf16x4*)(t_wr + 32) = tanh4(a1);
            bf16x4 xb = { (bf16)xn.x, (bf16)xn.y, (bf16)xn.z, (bf16)xn.w };
            *(bf16x4*)x_wr = xb;                              // x(t+1) -> h
            int t2 = (t + 2 < NT) ? (t + 2) : (NT - 1);
            xn = *(const float4*)(xsrc + (size_t)t2 * ND);    // prefetch x(t+2)
        }
        BAR();

        // ---- P2: B(t); xf reads + A_x(t+1) in shadow; gates; hc in place ----
        {
            f32x4 b0 = bB, b1 = {0.f,0.f,0.f,0.f};
            PRIO1();
            #pragma unroll
            for (int kt = 0; kt < 4; ++kt){
                bf16x8 tv = *(const bf16x8*)(t_rd + kt*64);
                if (kt & 1) b1 = mfma16(wB[kt], tv, b1);
                else        b0 = mfma16(wB[kt], tv, b0);
            }
            xf0 = *(const bf16x8*)(h_x_rd +   0);
            xf1 = *(const bf16x8*)(h_x_rd +  64);
            xf2 = *(const bf16x8*)(h_x_rd + 128);
            xf3 = *(const bf16x8*)(h_x_rd + 192);
            f32x4 ax0 = bA[0], ax1 = bA[1];
            ax0 = mfma16(wAx[0], xf0, ax0);  ax1 = mfma16(wAx[1], xf0, ax1);
            ax0 = mfma16(wAx[2], xf1, ax0);  ax1 = mfma16(wAx[3], xf1, ax1);
            ax0 = mfma16(wAx[4], xf2, ax0);  ax1 = mfma16(wAx[5], xf2, ax1);
            ax0 = mfma16(wAx[6], xf3, ax0);  ax1 = mfma16(wAx[7], xf3, ax1);
            PRIO0();
            Ax0 = ax0; Ax1 = ax1;
            f32x4 bs = b0 + b1;
            float g0 = fast_sigmoid(bs[0]);
            float g1 = fast_sigmoid(bs[1]);
            float g2 = fast_sigmoid(bs[2]);
            float g3 = fast_sigmoid(bs[3]);
            if (UG){
                ug_reg[0] = g0; ug_reg[1] = g1; ug_reg[2] = g2; ug_reg[3] = g3;
                *(f32x4*)&u_lds[lc][fB + lq*4] = ug_reg;
            } else {
                bf16x4 yv = *(const bf16x4*)(ys_rw);
                bf16x4 sv = *(const bf16x4*)(ys_rw + 128);
                bf16x4 hy = { (bf16)((float)yv[0]*g0), (bf16)((float)yv[1]*g1),
                              (bf16)((float)yv[2]*g2), (bf16)((float)yv[3]*g3) };
                bf16x4 hs = { (bf16)((float)sv[0]*g0), (bf16)((float)sv[1]*g1),
                              (bf16)((float)sv[2]*g2), (bf16)((float)sv[3]*g3) };
                *(bf16x4*)(ys_rw)       = hy;     // hc y*r over y cols
                *(bf16x4*)(ys_rw + 128) = hs;     // hc s*r over s cols
            }
        }
        BAR();

        // ---- P3: C_hc(t) (acc = carried C_x(t)); C_x(t+1); u pre-read ----
        {
            if (!UG) uu = *(const f32x4*)&u_lds[lc][fB + lq*4];
            f32x4 c0 = Cx, c1 = {0.f,0.f,0.f,0.f};
            PRIO1();
            #pragma unroll
            for (int kt = 0; kt < 4; ++kt){
                bf16x8 hv = *(const bf16x8*)(h_ys_rd + kt*64);
                if (kt & 1) c1 = mfma16(wCh[kt], hv, c1);
                else        c0 = mfma16(wCh[kt], hv, c0);
            }
            f32x4 cx = bC;
            cx = mfma16(wCx[0], xf0, cx);
            cx = mfma16(wCx[1], xf1, cx);
            cx = mfma16(wCx[2], xf2, cx);
            cx = mfma16(wCx[3], xf3, cx);
            PRIO0();
            Cx = cx;
            f32x4 cs = c0 + c1;
            *(bf16x4*)tn_wr = tanh4(cs);
        }
        BAR();

        // ---- P4: D(t); EMA (u register-only); publish y,s bf16 ----
        {
            f32x4 d0 = bD, d1 = {0.f,0.f,0.f,0.f};
            PRIO1();
            #pragma unroll
            for (int kt = 0; kt < 4; ++kt){
                bf16x8 tv = *(const bf16x8*)(tn_rd + kt*64);
                if (kt & 1) d1 = mfma16(wD[kt], tv, d1);
                else        d0 = mfma16(wD[kt], tv, d0);
            }
            PRIO0();
            f32x4 ds = d0 + d1;
            f32x4 u4 = UG ? ug_reg : uu;
            #pragma unroll
            for (int i = 0; i < 4; ++i){
                float v = UG ? ds[i] : fabsf(ds[i]);
                st[i] = fmaf(u4[i], st[i] - v, v);
            }
            bf16x4 hn = { (bf16)st[0], (bf16)st[1], (bf16)st[2], (bf16)st[3] };
            *(bf16x4*)h_st_wr = hn;
        }
        BAR();
    }

    // ---------------- output: yT (4096x64) then sT (4096x64), fp32 ----------
    {
        size_t gr = (size_t)(row0 + lc);
        float4 v = make_float4(st[0], st[1], st[2], st[3]);
        if (UG) *(float4*)&out[gr*64 + fD + lq*4] = v;
        else    *(float4*)&out[(size_t)NB*64 + gr*64 + (fD - 64) + lq*4] = v;
    }
}

extern "C" void kernel_launch(void* const* d_in, const int* in_sizes, int n_in,
                              void* d_out, int out_size, void* d_ws, size_t ws_size,
                              hipStream_t stream) {
    const float* data  = (const float*)d_in[0];
    // d_in[1] = time_steps — unused by the reference computation
    const float* ug_w1 = (const float*)d_in[2];
    const float* ug_b1 = (const float*)d_in[3];
    const float* ug_w2 = (const float*)d_in[4];
    const float* ug_b2 = (const float*)d_in[5];
    const float* rg_w1 = (const float*)d_in[6];
    const float* rg_b1 = (const float*)d_in[7];
    const float* rg_w2 = (const float*)d_in[8];
    const float* rg_b2 = (const float*)d_in[9];
    const float* ns_w1 = (const float*)d_in[10];
    const float* ns_b1 = (const float*)d_in[11];
    const float* ns_w2 = (const float*)d_in[12];
    const float* ns_b2 = (const float*)d_in[13];

    hipLaunchKernelGGL(vae_rnn, dim3(NB/16), dim3(512), 0, stream,
                       data, ug_w1, ug_b1, ug_w2, ug_b2,
                       rg_w1, rg_b1, rg_w2, rg_b2,
                       ns_w1, ns_b1, ns_w2, ns_b2,
                       (float*)d_out);
}

// Round 13
// 325.678 us; speedup vs baseline: 1.5876x; 1.0218x over previous
//
#include <hip/hip_runtime.h>
#include <hip/hip_bf16.h>

// VAE_RNN: B=4096, T=200, D=128, L=64, H=128, CIN=2L+D=256
// Persistent-block RNN, 256 blocks x 512 threads (8 symmetric waves),
// 16 rows/block, 200 steps. Weights register-resident.
// FINAL (= R8, measured best 324us): A and C split into ys-part (critical
// path) and x-part (state-independent). x(t+1) staged one step early; A_x(t+1)
// and C_x(t+1) run in P2/P3 latency shadows and carry across the step
// boundary in accumulator registers (MFMA C-operand = the carry).
//   P1: A_ys(t) [8 MFMA, acc=carried Ax] -> tanh -> t_lds
//       + publish x(t+1) to h, prefetch x(t+2) from HBM
//   P2: B(t) [4 MFMA] -> sigmoid; xf reads + A_x(t+1) [8 MFMA] in shadow;
//       u-waves: u -> regs+u_lds | r-waves: hc = y*r, s*r written IN PLACE
//   P3: C_hc(t) [4 MFMA, acc=carried Cx] -> tanh -> tn_lds; C_x(t+1) [4 MFMA]
//   P4: D(t) [4 MFMA] -> EMA (fp32 regs) -> publish y,s bf16
// 4 lgkm-only barriers/step (vmcnt stays in flight across barriers).
// Perimeter of refuted alternatives: 1 wave/SIMD (R4), 4 waves/SIMD via
// launch-bounds (R5: spill), wave-group specialization (R6), 8-row stream
// ping-pong (R7: garbage MFMA), global-direct x frags (R9: uncoalesced),
// reads moved into P1 (R10/R11), setprio on lockstep phases (R12).

#define NB 4096
#define NT 200
#define ND 128
#define HS 528      // h/t row stride bytes
#define TS 272      // tn row stride bytes

typedef __bf16 bf16;
typedef __attribute__((ext_vector_type(8))) __bf16 bf16x8;
typedef __attribute__((ext_vector_type(4))) __bf16 bf16x4;
typedef __attribute__((ext_vector_type(4))) float f32x4;

#define BAR() asm volatile("s_waitcnt lgkmcnt(0)\n\ts_barrier" ::: "memory")

__device__ __forceinline__ f32x4 mfma16(bf16x8 a, bf16x8 b, f32x4 c){
    return __builtin_amdgcn_mfma_f32_16x16x32_bf16(a, b, c, 0, 0, 0);
}
// inf-safe, branch-free
__device__ __forceinline__ float fast_tanh(float x){
    float e = __expf(2.f * x);
    return 1.f - 2.f * __builtin_amdgcn_rcpf(e + 1.f);
}
__device__ __forceinline__ float fast_sigmoid(float x){
    return __builtin_amdgcn_rcpf(1.f + __expf(-x));
}
__device__ __forceinline__ bf16x4 tanh4(f32x4 a){
    bf16x4 o;
    o[0] = (bf16)fast_tanh(a[0]);
    o[1] = (bf16)fast_tanh(a[1]);
    o[2] = (bf16)fast_tanh(a[2]);
    o[3] = (bf16)fast_tanh(a[3]);
    return o;
}
__device__ __forceinline__ f32x4 bias4(const float* b, int f){
    f32x4 r; r[0]=b[f]; r[1]=b[f+1]; r[2]=b[f+2]; r[3]=b[f+3]; return r;
}

__global__ __launch_bounds__(512, 2)
void vae_rnn(const float* __restrict__ data,
             const float* __restrict__ ug_w1, const float* __restrict__ ug_b1,
             const float* __restrict__ ug_w2, const float* __restrict__ ug_b2,
             const float* __restrict__ rg_w1, const float* __restrict__ rg_b1,
             const float* __restrict__ rg_w2, const float* __restrict__ rg_b2,
             const float* __restrict__ ns_w1, const float* __restrict__ ns_b1,
             const float* __restrict__ ns_w2, const float* __restrict__ ns_b2,
             float* __restrict__ out)
{
    __shared__ __align__(16) char h_lds [16 * HS];   // [y|s(->hc)|x] bf16
    __shared__ __align__(16) char t_lds [16 * HS];   // tanh(l1) [ug|rg] bf16
    __shared__ __align__(16) char tn_lds[16 * TS];   // tanh(l1) ns bf16
    __shared__ float u_lds[16][68];                  // u gate fp32

    const int tid  = threadIdx.x;
    const int w    = tid >> 6;
    const int lane = tid & 63;
    const int lq   = lane >> 4;
    const int lc   = lane & 15;          // batch row within tile
    const int row0 = blockIdx.x * 16;

    const bool UG = (w < 4);             // ug side / u-role / mean-role
    const int fA = w * 32;               // A feats (256 over 8 waves)
    const int fB = (w & 3) * 16;         // B gate feats (64 per role)
    const int fC = w * 16;               // C feats (128 over 8 waves)
    const int fD = w * 16;               // D feats (mean 0:64, std 64:128)

    const float* W1 = UG ? ug_w1 : rg_w1;
    const float* B1 = UG ? ug_b1 : rg_b1;
    const float* W2 = UG ? ug_w2 : rg_w2;
    const float* B2 = UG ? ug_b2 : rg_b2;

    // ---------------- persistent weight fragments ----------------
    bf16x8 wAy[8], wAx[8]; f32x4 bA[2];
    #pragma unroll
    for (int j = 0; j < 2; ++j){
        int n = (fA + j*16 + lc) & 127;
        bA[j] = bias4(B1, (fA + j*16 + lq*4) & 127);
        #pragma unroll
        for (int kt = 0; kt < 4; ++kt){
            bf16x8 fy, fx;
            #pragma unroll
            for (int e = 0; e < 8; ++e){
                fy[e] = (bf16)W1[(      kt*32 + lq*8 + e)*128 + n];
                fx[e] = (bf16)W1[(128 + kt*32 + lq*8 + e)*128 + n];
            }
            wAy[kt*2 + j] = fy; wAx[kt*2 + j] = fx;
        }
    }
    bf16x8 wB[4]; f32x4 bB = bias4(B2, fB + lq*4);
    {
        int n = fB + lc;
        #pragma unroll
        for (int kt = 0; kt < 4; ++kt){
            bf16x8 f;
            #pragma unroll
            for (int e = 0; e < 8; ++e) f[e] = (bf16)W2[(kt*32 + lq*8 + e)*64 + n];
            wB[kt] = f;
        }
    }
    bf16x8 wCh[4], wCx[4]; f32x4 bC = bias4(ns_b1, fC + lq*4);
    {
        int n = fC + lc;
        #pragma unroll
        for (int kt = 0; kt < 4; ++kt){
            bf16x8 fh, fx;
            #pragma unroll
            for (int e = 0; e < 8; ++e){
                fh[e] = (bf16)ns_w1[(      kt*32 + lq*8 + e)*128 + n];
                fx[e] = (bf16)ns_w1[(128 + kt*32 + lq*8 + e)*128 + n];
            }
            wCh[kt] = fh; wCx[kt] = fx;
        }
    }
    bf16x8 wD[4]; f32x4 bD = bias4(ns_b2, fD + lq*4);
    {
        int n = fD + lc;
        #pragma unroll
        for (int kt = 0; kt < 4; ++kt){
            bf16x8 f;
            #pragma unroll
            for (int e = 0; e < 8; ++e) f[e] = (bf16)ns_w2[(kt*32 + lq*8 + e)*128 + n];
            wD[kt] = f;
        }
    }

    // ---------------- LDS pointers (loop-invariant) ----------------
    const char* h_ys_rd = h_lds + lc*HS + lq*16;          // + kt*64 (y,s / hc)
    const char* h_x_rd  = h_lds + lc*HS + 256 + lq*16;    // + kt*64 (x)
    char*       t_wr    = t_lds + lc*HS + 2*(fA + lq*4);  // + j*32
    const char* t_rd    = t_lds + lc*HS + lq*16 + (UG ? 0 : 256);
    char*       tn_wr   = tn_lds + lc*TS + 2*(fC + lq*4);
    const char* tn_rd   = tn_lds + lc*TS + lq*16;         // + kt*64
    char*       h_st_wr = h_lds + lc*HS + 2*(fD + lq*4);  // y/s publish
    char*       ys_rw   = h_lds + lc*HS + 2*(fB + lq*4);  // r-wave rw; +128 s

    // x stage mapping: thread -> (row, 4 floats)
    const int xr = tid >> 5;             // 0..15
    const int xc = (tid & 31) << 2;      // 0..124
    const float* xsrc = data + (size_t)(row0 + xr) * (size_t)(NT * ND) + xc;
    char* x_wr = h_lds + xr*HS + 256 + 2*xc;

    // ---------------- prologue ----------------
    *(bf16x4*)(h_lds + xr*HS + (tid & 31)*8) = (bf16x4){};   // zero y,s cols
    {
        float4 x0 = *(const float4*)xsrc;
        bf16x4 xb0 = { (bf16)x0.x, (bf16)x0.y, (bf16)x0.z, (bf16)x0.w };
        *(bf16x4*)x_wr = xb0;                                 // stage x(0)
    }
    BAR();
    f32x4 Ax0, Ax1, Cx;                  // carried x-partials (incl. bias)
    {
        bf16x8 x0f = *(const bf16x8*)(h_x_rd +   0);
        bf16x8 x1f = *(const bf16x8*)(h_x_rd +  64);
        bf16x8 x2f = *(const bf16x8*)(h_x_rd + 128);
        bf16x8 x3f = *(const bf16x8*)(h_x_rd + 192);
        Ax0 = bA[0]; Ax1 = bA[1]; Cx = bC;
        Ax0 = mfma16(wAx[0], x0f, Ax0);  Ax1 = mfma16(wAx[1], x0f, Ax1);
        Ax0 = mfma16(wAx[2], x1f, Ax0);  Ax1 = mfma16(wAx[3], x1f, Ax1);
        Ax0 = mfma16(wAx[4], x2f, Ax0);  Ax1 = mfma16(wAx[5], x2f, Ax1);
        Ax0 = mfma16(wAx[6], x3f, Ax0);  Ax1 = mfma16(wAx[7], x3f, Ax1);
        Cx  = mfma16(wCx[0], x0f, Cx);
        Cx  = mfma16(wCx[1], x1f, Cx);
        Cx  = mfma16(wCx[2], x2f, Cx);
        Cx  = mfma16(wCx[3], x3f, Cx);
    }
    float4 xn = *(const float4*)(xsrc + ND);   // x(1) for first P1 publish
    f32x4 st = {0.f,0.f,0.f,0.f};              // y-state (mean) / s-state (std)
    f32x4 ug_reg = {0.f,0.f,0.f,0.f};
    bf16x8 xf0, xf1, xf2, xf3;                 // x frags cached P2 -> P3
    BAR();   // x(0) frag reads complete before first P1's x(1) publish

    #pragma unroll 1
    for (int t = 0; t < NT; ++t){
        // ---- P1: A_ys(t), acc = carried A_x(t); publish x(t+1); prefetch ----
        {
            f32x4 a0 = Ax0, a1 = Ax1;
            #pragma unroll
            for (int kt = 0; kt < 4; ++kt){
                bf16x8 hv = *(const bf16x8*)(h_ys_rd + kt*64);
                a0 = mfma16(wAy[kt*2+0], hv, a0);
                a1 = mfma16(wAy[kt*2+1], hv, a1);
            }
            *(bf16x4*)(t_wr +  0) = tanh4(a0);
            *(bf16x4*)(t_wr + 32) = tanh4(a1);
            bf16x4 xb = { (bf16)xn.x, (bf16)xn.y, (bf16)xn.z, (bf16)xn.w };
            *(bf16x4*)x_wr = xb;                              // x(t+1) -> h
            int t2 = (t + 2 < NT) ? (t + 2) : (NT - 1);
            xn = *(const float4*)(xsrc + (size_t)t2 * ND);    // prefetch x(t+2)
        }
        BAR();

        // ---- P2: B(t); xf reads + A_x(t+1) in shadow; gates; hc in place ----
        {
            f32x4 b0 = bB, b1 = {0.f,0.f,0.f,0.f};
            #pragma unroll
            for (int kt = 0; kt < 4; ++kt){
                bf16x8 tv = *(const bf16x8*)(t_rd + kt*64);
                if (kt & 1) b1 = mfma16(wB[kt], tv, b1);
                else        b0 = mfma16(wB[kt], tv, b0);
            }
            xf0 = *(const bf16x8*)(h_x_rd +   0);
            xf1 = *(const bf16x8*)(h_x_rd +  64);
            xf2 = *(const bf16x8*)(h_x_rd + 128);
            xf3 = *(const bf16x8*)(h_x_rd + 192);
            f32x4 ax0 = bA[0], ax1 = bA[1];
            ax0 = mfma16(wAx[0], xf0, ax0);  ax1 = mfma16(wAx[1], xf0, ax1);
            ax0 = mfma16(wAx[2], xf1, ax0);  ax1 = mfma16(wAx[3], xf1, ax1);
            ax0 = mfma16(wAx[4], xf2, ax0);  ax1 = mfma16(wAx[5], xf2, ax1);
            ax0 = mfma16(wAx[6], xf3, ax0);  ax1 = mfma16(wAx[7], xf3, ax1);
            Ax0 = ax0; Ax1 = ax1;
            f32x4 bs = b0 + b1;
            float g0 = fast_sigmoid(bs[0]);
            float g1 = fast_sigmoid(bs[1]);
            float g2 = fast_sigmoid(bs[2]);
            float g3 = fast_sigmoid(bs[3]);
            if (UG){
                ug_reg[0] = g0; ug_reg[1] = g1; ug_reg[2] = g2; ug_reg[3] = g3;
                *(f32x4*)&u_lds[lc][fB + lq*4] = ug_reg;
            } else {
                bf16x4 yv = *(const bf16x4*)(ys_rw);
                bf16x4 sv = *(const bf16x4*)(ys_rw + 128);
                bf16x4 hy = { (bf16)((float)yv[0]*g0), (bf16)((float)yv[1]*g1),
                              (bf16)((float)yv[2]*g2), (bf16)((float)yv[3]*g3) };
                bf16x4 hs = { (bf16)((float)sv[0]*g0), (bf16)((float)sv[1]*g1),
                              (bf16)((float)sv[2]*g2), (bf16)((float)sv[3]*g3) };
                *(bf16x4*)(ys_rw)       = hy;     // hc y*r over y cols
                *(bf16x4*)(ys_rw + 128) = hs;     // hc s*r over s cols
            }
        }
        BAR();

        // ---- P3: C_hc(t) (acc = carried C_x(t)); C_x(t+1) on cached xf ----
        {
            f32x4 c0 = Cx, c1 = {0.f,0.f,0.f,0.f};
            #pragma unroll
            for (int kt = 0; kt < 4; ++kt){
                bf16x8 hv = *(const bf16x8*)(h_ys_rd + kt*64);
                if (kt & 1) c1 = mfma16(wCh[kt], hv, c1);
                else        c0 = mfma16(wCh[kt], hv, c0);
            }
            f32x4 cx = bC;
            cx = mfma16(wCx[0], xf0, cx);
            cx = mfma16(wCx[1], xf1, cx);
            cx = mfma16(wCx[2], xf2, cx);
            cx = mfma16(wCx[3], xf3, cx);
            Cx = cx;
            f32x4 cs = c0 + c1;
            *(bf16x4*)tn_wr = tanh4(cs);
        }
        BAR();

        // ---- P4: D(t); EMA; publish y,s bf16 ----
        {
            f32x4 uu = ug_reg;
            if (!UG) uu = *(const f32x4*)&u_lds[lc][fB + lq*4];
            f32x4 d0 = bD, d1 = {0.f,0.f,0.f,0.f};
            #pragma unroll
            for (int kt = 0; kt < 4; ++kt){
                bf16x8 tv = *(const bf16x8*)(tn_rd + kt*64);
                if (kt & 1) d1 = mfma16(wD[kt], tv, d1);
                else        d0 = mfma16(wD[kt], tv, d0);
            }
            f32x4 ds = d0 + d1;
            #pragma unroll
            for (int i = 0; i < 4; ++i){
                float v = UG ? ds[i] : fabsf(ds[i]);
                st[i] = fmaf(uu[i], st[i] - v, v);
            }
            bf16x4 hn = { (bf16)st[0], (bf16)st[1], (bf16)st[2], (bf16)st[3] };
            *(bf16x4*)h_st_wr = hn;
        }
        BAR();
    }

    // ---------------- output: yT (4096x64) then sT (4096x64), fp32 ----------
    {
        size_t gr = (size_t)(row0 + lc);
        float4 v = make_float4(st[0], st[1], st[2], st[3]);
        if (UG) *(float4*)&out[gr*64 + fD + lq*4] = v;
        else    *(float4*)&out[(size_t)NB*64 + gr*64 + (fD - 64) + lq*4] = v;
    }
}

extern "C" void kernel_launch(void* const* d_in, const int* in_sizes, int n_in,
                              void* d_out, int out_size, void* d_ws, size_t ws_size,
                              hipStream_t stream) {
    const float* data  = (const float*)d_in[0];
    // d_in[1] = time_steps — unused by the reference computation
    const float* ug_w1 = (const float*)d_in[2];
    const float* ug_b1 = (const float*)d_in[3];
    const float* ug_w2 = (const float*)d_in[4];
    const float* ug_b2 = (const float*)d_in[5];
    const float* rg_w1 = (const float*)d_in[6];
    const float* rg_b1 = (const float*)d_in[7];
    const float* rg_w2 = (const float*)d_in[8];
    const float* rg_b2 = (const float*)d_in[9];
    const float* ns_w1 = (const float*)d_in[10];
    const float* ns_b1 = (const float*)d_in[11];
    const float* ns_w2 = (const float*)d_in[12];
    const float* ns_b2 = (const float*)d_in[13];

    hipLaunchKernelGGL(vae_rnn, dim3(NB/16), dim3(512), 0, stream,
                       data, ug_w1, ug_b1, ug_w2, ug_b2,
                       rg_w1, rg_b1, rg_w2, rg_b2,
                       ns_w1, ns_b1, ns_w2, ns_b2,
                       (float*)d_out);
}